// Round 4
// baseline (144.158 us; speedup 1.0000x reference)
//
#include <hip/hip_runtime.h>
#include <hip/hip_bf16.h>

// Geometry fixed by reference: B=16, Lq=Lk=2048, D=Dv=64, fp32.
// d_out = out [16,2048,64] ++ w [16,2048,2048].
#define B_ 16
#define L_ 2048
#define D_ 64
#define NROWS (B_ * L_)

typedef _Float16 half8  __attribute__((ext_vector_type(8)));
typedef _Float16 half4v __attribute__((ext_vector_type(4)));
typedef float    f32x4  __attribute__((ext_vector_type(4)));

#define AS1 __attribute__((address_space(1)))
#define AS3 __attribute__((address_space(3)))

__device__ __forceinline__ void gll16(const void* g, void* l) {
    __builtin_amdgcn_global_load_lds((AS1 const unsigned int*)g,
                                     (AS3 unsigned int*)l, 16, 0, 0);
}

// fp16 hi/lo split of x*scale: hi = fp16(x*scale), lo = fp16((x*scale-hi)*2048)
__device__ __forceinline__ void cvt8(float4 x, float4 y, float scale,
                                     half8& hi, half8& lo) {
    float a[8] = {x.x, x.y, x.z, x.w, y.x, y.y, y.z, y.w};
    #pragma unroll
    for (int j = 0; j < 8; ++j) {
        float s = a[j] * scale;
        _Float16 h = (_Float16)s;
        hi[j] = h;
        lo[j] = (_Float16)((s - (float)h) * 2048.0f);
    }
}

// ---------------------------------------------------------------------------
// Kernel P: K fp32 -> kext rows of 256 B: [bl(64) | bh(64)] fp16.
// (Q is converted in-register inside the score blocks.)
// ---------------------------------------------------------------------------
__global__ __launch_bounds__(256)
void cvt_k(const float* __restrict__ k, _Float16* __restrict__ kext)
{
    int i = blockIdx.x * 256 + threadIdx.x;   // quad id over 16*2048*64/4
    int r = i >> 4;
    int d = (i & 15) << 2;

    float4 kv = *reinterpret_cast<const float4*>(k + (size_t)r * D_ + d);
    half4v bh = { (_Float16)kv.x, (_Float16)kv.y, (_Float16)kv.z, (_Float16)kv.w };
    half4v bl = { (_Float16)((kv.x - (float)bh[0]) * 2048.0f),
                  (_Float16)((kv.y - (float)bh[1]) * 2048.0f),
                  (_Float16)((kv.z - (float)bh[2]) * 2048.0f),
                  (_Float16)((kv.w - (float)bh[3]) * 2048.0f) };

    *reinterpret_cast<half4v*>(kext + (size_t)r * 128 + d)      = bl;
    *reinterpret_cast<half4v*>(kext + (size_t)r * 128 + 64 + d) = bh;
}

// ---------------------------------------------------------------------------
// Kernel A (fused): even blockIdx = score block (MFMA scores + sum-exp2 +
// top-4), odd blockIdx = fill block (nontemporal zero-fill of dense w).
// Fill is block-decoupled: no barrier ever waits on a w-store.
// ---------------------------------------------------------------------------
__global__ __launch_bounds__(256)
void sdpa_fused(const float* __restrict__ q,
                const _Float16* __restrict__ kext,
                float* __restrict__ wout,
                float* __restrict__ wsv,
                int*   __restrict__ wsi)
{
    __shared__ __align__(16) _Float16 Ks[2][64 * 128];   // 32 KB total

    const int bid = blockIdx.x;
    const int tid = threadIdx.x;

    if (bid & 1) {
        // ---- fill block: zero 512 KB of w (all 16 batches covered) ----
        const int fid = bid >> 1;                         // 0..511
        f32x4* p = reinterpret_cast<f32x4*>(wout) + (size_t)fid * 32768 + tid;
        f32x4 z = {0.f, 0.f, 0.f, 0.f};
        #pragma unroll 4
        for (int i = 0; i < 128; ++i)
            __builtin_nontemporal_store(z, p + (size_t)i * 256);
        return;
    }

    // ---- score block ----
    const int sid  = bid >> 1;          // 0..511
    const int b    = sid >> 5;
    const int row0 = (sid & 31) * 64;
    const int w    = tid >> 6;
    const int lane = tid & 63;
    const int c    = lane & 15;         // MFMA col (key) / row within wave tile
    const int g    = lane >> 4;         // k-slot group

    const char* ke = (const char*)(kext + (size_t)b * L_ * 128);

    // K-tile staging: LDS linear dest, inverse-swizzled global source.
    // Read layout: byte(kl, cb) = kl*256 + ((cb ^ (kl&7))<<4).
    auto stageK = [&](int buf, int kt) {
        const char* src = ke + (size_t)kt * 16384;
        #pragma unroll
        for (int t = 0; t < 4; ++t) {
            int o  = w * 4096 + t * 1024;        // wave-uniform LDS base
            int rr = (o >> 8) + g;               // key row this lane covers
            int gb = rr * 256 + ((c ^ (rr & 7)) << 4);
            gll16(src + gb, (char*)(Ks[buf]) + o);
        }
    };

    stageK(0, 0);

    // ---- Q fragments directly from global (16 floats/lane), converted
    // in-register with the log2(e)/8 scale folded in ----
    const float CQ = 0.18033688011112042f;   // log2(e)/8
    half8 qf0, qf1, qf2, qf3;
    {
        const float* qr = q + (size_t)(b * L_ + row0 + 16 * w + c) * D_ + 8 * g;
        float4 f0 = *reinterpret_cast<const float4*>(qr);
        float4 f1 = *reinterpret_cast<const float4*>(qr + 4);
        float4 f2 = *reinterpret_cast<const float4*>(qr + 32);
        float4 f3 = *reinterpret_cast<const float4*>(qr + 36);
        cvt8(f0, f1, CQ, qf0, qf2);   // ah,al for k-cols [0,32)
        cvt8(f2, f3, CQ, qf1, qf3);   // ah,al for k-cols [32,64)
    }

    float Zacc[4];
    float tv[4][4];
    int   ti[4][3];
    #pragma unroll
    for (int r = 0; r < 4; ++r) {
        Zacc[r] = 0.0f;
        #pragma unroll
        for (int t = 0; t < 4; ++t) tv[r][t] = -3.0e38f;
        #pragma unroll
        for (int t = 0; t < 3; ++t) ti[r][t] = 0;
    }

    __syncthreads();   // K0 staged

    int buf = 0;
    for (int kt = 0; kt < 32; ++kt) {
        if (kt + 1 < 32) stageK(buf ^ 1, kt + 1);

        const char* kb = (const char*)(Ks[buf]);
        #pragma unroll
        for (int nt = 0; nt < 4; ++nt) {
            int kl = nt * 16 + c;
            int x  = kl & 7;
            const char* kr = kb + kl * 256;
            half8 bf0 = *(const half8*)(kr + (((0  + g) ^ x) << 4)); // bl [0,32)
            half8 bf1 = *(const half8*)(kr + (((4  + g) ^ x) << 4)); // bl [32,64)
            half8 bf2 = *(const half8*)(kr + (((8  + g) ^ x) << 4)); // bh [0,32)
            half8 bf3 = *(const half8*)(kr + (((12 + g) ^ x) << 4)); // bh [32,64)

            f32x4 a1 = {0.f, 0.f, 0.f, 0.f};
            f32x4 a2 = {0.f, 0.f, 0.f, 0.f};
            a1 = __builtin_amdgcn_mfma_f32_16x16x32_f16(qf0, bf2, a1, 0, 0, 0);
            a2 = __builtin_amdgcn_mfma_f32_16x16x32_f16(qf0, bf0, a2, 0, 0, 0);
            a1 = __builtin_amdgcn_mfma_f32_16x16x32_f16(qf1, bf3, a1, 0, 0, 0);
            a2 = __builtin_amdgcn_mfma_f32_16x16x32_f16(qf1, bf1, a2, 0, 0, 0);
            a2 = __builtin_amdgcn_mfma_f32_16x16x32_f16(qf2, bf2, a2, 0, 0, 0);
            a2 = __builtin_amdgcn_mfma_f32_16x16x32_f16(qf3, bf3, a2, 0, 0, 0);

            const int idx = kt * 64 + nt * 16 + c;
            #pragma unroll
            for (int r = 0; r < 4; ++r) {
                float sp = fmaf(a2[r], 4.8828125e-4f, a1[r]);  // + 2^-11 * lo
                Zacc[r] += exp2f(sp);
                bool c0 = sp > tv[r][0];
                bool c1 = sp > tv[r][1];
                bool c2 = sp > tv[r][2];
                bool c3 = sp > tv[r][3];
                tv[r][3] = c2 ? tv[r][2] : (c3 ? sp  : tv[r][3]);
                tv[r][2] = c1 ? tv[r][1] : (c2 ? sp  : tv[r][2]);
                ti[r][2] = c1 ? ti[r][1] : (c2 ? idx : ti[r][2]);
                tv[r][1] = c0 ? tv[r][0] : (c1 ? sp  : tv[r][1]);
                ti[r][1] = c0 ? ti[r][0] : (c1 ? idx : ti[r][1]);
                tv[r][0] = c0 ? sp  : tv[r][0];
                ti[r][0] = c0 ? idx : ti[r][0];
            }
        }
        __syncthreads();
        buf ^= 1;
    }

    // ---- per-row merge across the 16 lanes sharing each row ----
    #pragma unroll
    for (int r = 0; r < 4; ++r) {
        float Z = Zacc[r];
        #pragma unroll
        for (int m = 8; m; m >>= 1) Z += __shfl_xor(Z, m, 16);

        int p = 0;
        float mv4[4]; int mi4[3];
        #pragma unroll
        for (int t = 0; t < 4; ++t) {
            float cand  = (p == 0) ? tv[r][0] : (p == 1) ? tv[r][1]
                        : (p == 2) ? tv[r][2] : (p == 3) ? tv[r][3] : -3.0e38f;
            int   candi = (p == 0) ? ti[r][0] : (p == 1) ? ti[r][1]
                        : (p == 2) ? ti[r][2] : (p == 3) ? (0x40000000 | c)
                        : 0x7fffffff;
            float mv = cand; int mi = candi;
            #pragma unroll
            for (int m = 8; m; m >>= 1) {
                float ov = __shfl_xor(mv, m, 16);
                int   oi = __shfl_xor(mi, m, 16);
                if (ov > mv || (ov == mv && oi < mi)) { mv = ov; mi = oi; }
            }
            mv4[t] = mv;
            if (t < 3) mi4[t] = mi;
            if (candi == mi) ++p;
        }

        float invZ = 1.0f / Z;
        float p0 = exp2f(mv4[0]) * invZ;
        float p1 = exp2f(mv4[1]) * invZ;
        float p2 = exp2f(mv4[2]) * invZ;
        float p3 = exp2f(mv4[3]) * invZ;
        float delta = p3 + 1e-7f;
        float a0 = fmaxf(p0 - delta, 0.f);
        float a1 = fmaxf(p1 - delta, 0.f);
        float a2 = fmaxf(p2 - delta, 0.f);
        float rinv = 1.0f / (a0 + a1 + a2 + 1e-7f);
        if (c == 0) {
            int gr = b * L_ + row0 + 16 * w + 4 * g + r;
            *reinterpret_cast<float4*>(wsv + (size_t)gr * 4) =
                make_float4(a0 * rinv, a1 * rinv, a2 * rinv, 0.f);
            *reinterpret_cast<int4*>(wsi + (size_t)gr * 4) =
                make_int4(mi4[0], mi4[1], mi4[2], 0);
        }
    }
}

// ---------------------------------------------------------------------------
// Kernel B: out = sum_j w_j * v[idx_j]; scatter the <=3 nonzero w entries.
// ---------------------------------------------------------------------------
__global__ __launch_bounds__(256)
void sdpa_out_scatter(const float* __restrict__ v,
                      const float* __restrict__ wsv,
                      const int*   __restrict__ wsi,
                      float* __restrict__ out,
                      float* __restrict__ wout)
{
    int gr   = blockIdx.x * 4 + (threadIdx.x >> 6);
    int lane = threadIdx.x & 63;
    int b    = gr >> 11;

    float4 wv = *reinterpret_cast<const float4*>(wsv + (size_t)gr * 4);
    int4   iv = *reinterpret_cast<const int4*>(wsi + (size_t)gr * 4);

    const float* vb = v + (size_t)b * L_ * D_;
    float o = wv.x * vb[(size_t)iv.x * D_ + lane]
            + wv.y * vb[(size_t)iv.y * D_ + lane]
            + wv.z * vb[(size_t)iv.z * D_ + lane];
    out[(size_t)gr * D_ + lane] = o;

    if (lane < 3) {
        int   si = (lane == 0) ? iv.x : (lane == 1) ? iv.y : iv.z;
        float sw = (lane == 0) ? wv.x : (lane == 1) ? wv.y : wv.z;
        wout[(size_t)gr * L_ + si] = sw;
    }
}

extern "C" void kernel_launch(void* const* d_in, const int* in_sizes, int n_in,
                              void* d_out, int out_size, void* d_ws, size_t ws_size,
                              hipStream_t stream) {
    const float* q = (const float*)d_in[0];
    const float* k = (const float*)d_in[1];
    const float* v = (const float*)d_in[2];

    float* out  = (float*)d_out;
    float* wout = out + (size_t)B_ * L_ * D_;

    // Workspace layout (uses < 10 MB of d_ws):
    //   [kext: 16*2048*128 fp16 = 8 MiB][wsv: 512 KiB][wsi: 512 KiB]
    _Float16* kext = (_Float16*)d_ws;
    float* wsv = (float*)((char*)d_ws + (8u << 20));
    int*   wsi = (int*)((char*)d_ws + (8u << 20) + NROWS * 16);

    cvt_k<<<(B_ * L_ * D_) / (4 * 256), 256, 0, stream>>>(k, kext);

    // 512 score blocks (even bids) + 512 fill blocks (odd bids)
    sdpa_fused<<<1024, 256, 0, stream>>>(q, kext, wout, wsv, wsi);

    sdpa_out_scatter<<<NROWS / 4, 256, 0, stream>>>(v, wsv, wsi, out, wout);
}

// Round 5
// 120.889 us; speedup vs baseline: 1.1925x; 1.1925x over previous
//
#include <hip/hip_runtime.h>
#include <hip/hip_bf16.h>

// Geometry fixed by reference: B=16, Lq=Lk=2048, D=Dv=64, fp32.
// d_out = out [16,2048,64] ++ w [16,2048,2048].
#define B_ 16
#define L_ 2048
#define D_ 64
#define NROWS (B_ * L_)

typedef _Float16 half8 __attribute__((ext_vector_type(8)));
typedef float    f32x4 __attribute__((ext_vector_type(4)));

__device__ __forceinline__ float fexp2(float x) {
    float r; asm("v_exp_f32 %0, %1" : "=v"(r) : "v"(x)); return r;
}
__device__ __forceinline__ unsigned umed3(unsigned a, unsigned b, unsigned c) {
    unsigned d; asm("v_med3_u32 %0, %1, %2, %3" : "=v"(d) : "v"(a), "v"(b), "v"(c));
    return d;
}
// monotone float -> uint order-preserving transform
__device__ __forceinline__ unsigned fkey(float x) {
    unsigned b = __float_as_uint(x);
    return b ^ ((unsigned)(((int)b) >> 31) | 0x80000000u);
}

// ---------------------------------------------------------------------------
// Kernel P: K fp32 -> fp16, row-major (row = 64 halves = 128 B).
// ---------------------------------------------------------------------------
__global__ __launch_bounds__(256)
void cvt_k(const float* __restrict__ k, _Float16* __restrict__ kext)
{
    size_t i = (size_t)blockIdx.x * 256 + threadIdx.x;   // 8 floats each
    const float4* src = reinterpret_cast<const float4*>(k) + i * 2;
    float4 a = src[0], b = src[1];
    half8 h = { (_Float16)a.x, (_Float16)a.y, (_Float16)a.z, (_Float16)a.w,
                (_Float16)b.x, (_Float16)b.y, (_Float16)b.z, (_Float16)b.w };
    *reinterpret_cast<half8*>(kext + i * 8) = h;
}

// ---------------------------------------------------------------------------
// Kernel A: bid < 1024 -> score block (32 q-rows, fp16 MFMA scores straight
// from L2-resident kext, online sum-exp2 + packed-uint top-4 ladder).
// bid >= 1024 -> fill block (zero w rows [0,16384)).
// Score waves: wr = row half, wk = key half; wk-pair merge via LDS, then
// 16-lane tournament per row. Output per row: 4 indices + Z.
// ---------------------------------------------------------------------------
__global__ __launch_bounds__(256)
void sdpa_score(const float* __restrict__ q,
                const _Float16* __restrict__ kext,
                float* __restrict__ wout,
                int4*  __restrict__ wsi,
                float* __restrict__ wsv)
{
    __shared__ float Ms[2][64][21];   // wk-merge scratch (pad 21: bank-spread)

    const int bid = blockIdx.x;
    const int tid = threadIdx.x;

    if (bid >= 1024) {
        // ---- fill block: zero 512 KB of w (rows [0,16384) covered) ----
        const int fid = bid - 1024;                       // 0..255
        f32x4* p = reinterpret_cast<f32x4*>(wout) + (size_t)fid * 32768 + tid;
        f32x4 z = {0.f, 0.f, 0.f, 0.f};
        #pragma unroll 4
        for (int i = 0; i < 128; ++i)
            __builtin_nontemporal_store(z, p + (size_t)i * 256);
        return;
    }

    // ---- score block ----
    const int b    = bid >> 6;           // batch
    const int row0 = (bid & 63) * 32;    // 32 rows per block
    const int w    = tid >> 6;
    const int lane = tid & 63;
    const int wr   = w & 1;              // row half (16 rows)
    const int wk   = w >> 1;             // key half (1024 keys)
    const int c    = lane & 15;
    const int g    = lane >> 4;

    // Q fragment (A operand): row (row0+16wr+c), k = d in [8g,8g+8) | [32+8g,..)
    const float CQ = 0.18033688011112042f;   // log2(e)/8
    half8 qf0, qf1;
    {
        const float* qr = q + ((size_t)(b * L_ + row0 + 16 * wr + c)) * D_ + 8 * g;
        float4 f0 = *reinterpret_cast<const float4*>(qr);
        float4 f1 = *reinterpret_cast<const float4*>(qr + 4);
        float4 f2 = *reinterpret_cast<const float4*>(qr + 32);
        float4 f3 = *reinterpret_cast<const float4*>(qr + 36);
        qf0 = half8{ (_Float16)(f0.x*CQ), (_Float16)(f0.y*CQ), (_Float16)(f0.z*CQ),
                     (_Float16)(f0.w*CQ), (_Float16)(f1.x*CQ), (_Float16)(f1.y*CQ),
                     (_Float16)(f1.z*CQ), (_Float16)(f1.w*CQ) };
        qf1 = half8{ (_Float16)(f2.x*CQ), (_Float16)(f2.y*CQ), (_Float16)(f2.z*CQ),
                     (_Float16)(f2.w*CQ), (_Float16)(f3.x*CQ), (_Float16)(f3.y*CQ),
                     (_Float16)(f3.z*CQ), (_Float16)(f3.w*CQ) };
    }

    const char* ke = (const char*)(kext + (size_t)b * L_ * D_);

    float    Z[4]  = {0.f, 0.f, 0.f, 0.f};
    unsigned tl[4][4];
    #pragma unroll
    for (int r = 0; r < 4; ++r)
        #pragma unroll
        for (int s = 0; s < 4; ++s) tl[r][s] = 0u;

    // sweep 1024 keys (this wave's half), 16 keys per step, no LDS staging
    #pragma unroll 4
    for (int t = 0; t < 64; ++t) {
        const int kl = wk * 1024 + t * 16 + c;            // key id in batch
        const char* kp = ke + (size_t)kl * 128 + g * 16;
        half8 b0 = *reinterpret_cast<const half8*>(kp);        // d [8g,8g+8)
        half8 b1 = *reinterpret_cast<const half8*>(kp + 64);   // d [32+8g,..)

        f32x4 a = {0.f, 0.f, 0.f, 0.f};
        a = __builtin_amdgcn_mfma_f32_16x16x32_f16(qf0, b0, a, 0, 0, 0);
        a = __builtin_amdgcn_mfma_f32_16x16x32_f16(qf1, b1, a, 0, 0, 0);

        #pragma unroll
        for (int r = 0; r < 4; ++r) {
            float sp = a[r];                  // log2-domain score
            Z[r] += fexp2(sp);
            unsigned pk = (fkey(sp) & 0xFFFFF800u) | (unsigned)kl;
            unsigned n1 = umed3(pk, tl[r][0], tl[r][1]);
            unsigned n2 = umed3(pk, tl[r][1], tl[r][2]);
            unsigned n3 = umed3(pk, tl[r][2], tl[r][3]);
            tl[r][0] = max(tl[r][0], pk);
            tl[r][1] = n1; tl[r][2] = n2; tl[r][3] = n3;
        }
    }

    // ---- wk-pair merge through LDS ----
    if (wk == 1) {
        #pragma unroll
        for (int r = 0; r < 4; ++r) {
            Ms[wr][lane][r] = Z[r];
            #pragma unroll
            for (int s = 0; s < 4; ++s)
                Ms[wr][lane][4 + r * 4 + s] = __uint_as_float(tl[r][s]);
        }
    }
    __syncthreads();
    if (wk == 1) return;

    #pragma unroll
    for (int r = 0; r < 4; ++r) {
        float Zr = Z[r] + Ms[wr][lane][r];
        #pragma unroll
        for (int s = 0; s < 4; ++s) {
            unsigned pk = __float_as_uint(Ms[wr][lane][4 + r * 4 + s]);
            unsigned n1 = umed3(pk, tl[r][0], tl[r][1]);
            unsigned n2 = umed3(pk, tl[r][1], tl[r][2]);
            unsigned n3 = umed3(pk, tl[r][2], tl[r][3]);
            tl[r][0] = max(tl[r][0], pk);
            tl[r][1] = n1; tl[r][2] = n2; tl[r][3] = n3;
        }
        #pragma unroll
        for (int m = 8; m; m >>= 1) Zr += __shfl_xor(Zr, m, 16);

        // 16-lane tournament: global top-4 (packed keys unique -> pure umax)
        int p = 0;
        unsigned win[4];
        #pragma unroll
        for (int t4 = 0; t4 < 4; ++t4) {
            unsigned cand = (p == 0) ? tl[r][0] : (p == 1) ? tl[r][1]
                          : (p == 2) ? tl[r][2] : (p == 3) ? tl[r][3] : 0u;
            unsigned mv = cand;
            #pragma unroll
            for (int m = 8; m; m >>= 1) {
                unsigned ov = __shfl_xor(mv, m, 16);
                mv = mv > ov ? mv : ov;
            }
            win[t4] = mv;
            if (cand == mv) ++p;
        }

        if (c == 0) {
            int gr = b * L_ + row0 + 16 * wr + 4 * g + r;
            wsi[gr] = make_int4((int)(win[0] & 2047u), (int)(win[1] & 2047u),
                                (int)(win[2] & 2047u), (int)(win[3] & 2047u));
            wsv[gr] = Zr;
        }
    }
}

// ---------------------------------------------------------------------------
// Kernel C: per row, exact fp32 rescore of the 4 candidates, weights,
// out = sum w_j v[idx_j], scatter w. Blocks owning rows [16384,32768) zero
// their own 4 w-rows first (the fill blocks covered [0,16384)).
// ---------------------------------------------------------------------------
__global__ __launch_bounds__(256)
void refine_out(const float* __restrict__ q,
                const float* __restrict__ k,
                const float* __restrict__ v,
                const int4*  __restrict__ wsi,
                const float* __restrict__ wsv,
                float* __restrict__ out,
                float* __restrict__ wout)
{
    const int gr0 = blockIdx.x * 4;
    const int tid = threadIdx.x;

    if (gr0 >= 16384) {   // zero own 4 w-rows (block-uniform branch)
        f32x4 z = {0.f, 0.f, 0.f, 0.f};
        f32x4* p = reinterpret_cast<f32x4*>(wout + (size_t)gr0 * L_) + tid;
        #pragma unroll
        for (int i = 0; i < 8; ++i)
            __builtin_nontemporal_store(z, p + i * 256);
        __syncthreads();
    }

    const int gr   = gr0 + (tid >> 6);
    const int lane = tid & 63;
    const int b    = gr >> 11;

    int4  iv = wsi[gr];
    float Z  = wsv[gr];

    const float CQ = 0.18033688011112042f;   // log2(e)/8
    float qd = q[(size_t)gr * D_ + lane] * CQ;
    const float* kb = k + (size_t)b * L_ * D_;
    float t0 = qd * kb[(size_t)iv.x * D_ + lane];
    float t1 = qd * kb[(size_t)iv.y * D_ + lane];
    float t2 = qd * kb[(size_t)iv.z * D_ + lane];
    float t3 = qd * kb[(size_t)iv.w * D_ + lane];
    #pragma unroll
    for (int m = 32; m; m >>= 1) {
        t0 += __shfl_xor(t0, m);
        t1 += __shfl_xor(t1, m);
        t2 += __shfl_xor(t2, m);
        t3 += __shfl_xor(t3, m);
    }

    // P_j = Z * p_j ; all w math scaled by Z (exactly equivalent)
    float P0 = fexp2(t0), P1 = fexp2(t1), P2 = fexp2(t2), P3 = fexp2(t3);
    float Pmin = fminf(fminf(P0, P1), fminf(P2, P3));
    float eZ = 1e-7f * Z;
    float n0 = fmaxf(P0 - Pmin - eZ, 0.f);
    float n1 = fmaxf(P1 - Pmin - eZ, 0.f);
    float n2 = fmaxf(P2 - Pmin - eZ, 0.f);
    float n3 = fmaxf(P3 - Pmin - eZ, 0.f);
    float wi = 1.0f / (n0 + n1 + n2 + n3 + eZ);
    float w0 = n0 * wi, w1 = n1 * wi, w2 = n2 * wi, w3 = n3 * wi;

    const float* vb = v + (size_t)b * L_ * D_;
    float o = w0 * vb[(size_t)iv.x * D_ + lane]
            + w1 * vb[(size_t)iv.y * D_ + lane]
            + w2 * vb[(size_t)iv.z * D_ + lane]
            + w3 * vb[(size_t)iv.w * D_ + lane];
    out[(size_t)gr * D_ + lane] = o;

    if (lane < 4) {
        int   si = (lane == 0) ? iv.x : (lane == 1) ? iv.y : (lane == 2) ? iv.z : iv.w;
        float sw = (lane == 0) ? w0   : (lane == 1) ? w1   : (lane == 2) ? w2   : w3;
        wout[(size_t)gr * L_ + si] = sw;   // w for Pmin slot is exactly 0
    }
}

extern "C" void kernel_launch(void* const* d_in, const int* in_sizes, int n_in,
                              void* d_out, int out_size, void* d_ws, size_t ws_size,
                              hipStream_t stream) {
    const float* q = (const float*)d_in[0];
    const float* k = (const float*)d_in[1];
    const float* v = (const float*)d_in[2];

    float* out  = (float*)d_out;
    float* wout = out + (size_t)B_ * L_ * D_;

    // d_ws: [kext 4 MiB][wsi int4 x 32768 = 512 KiB][wsv 128 KiB]
    _Float16* kext = (_Float16*)d_ws;
    int4*  wsi = (int4*)((char*)d_ws + (4u << 20));
    float* wsv = (float*)((char*)d_ws + (4u << 20) + NROWS * 16);

    cvt_k<<<(B_ * L_ * D_) / (8 * 256), 256, 0, stream>>>(k, kext);

    // 1024 score blocks + 256 fill blocks
    sdpa_score<<<1280, 256, 0, stream>>>(q, kext, wout, wsi, wsv);

    refine_out<<<NROWS / 4, 256, 0, stream>>>(q, k, v, wsi, wsv, out, wout);
}

// Round 6
// 97.422 us; speedup vs baseline: 1.4797x; 1.2409x over previous
//
#include <hip/hip_runtime.h>
#include <hip/hip_bf16.h>

// Geometry fixed by reference: B=16, Lq=Lk=2048, D=Dv=64, fp32.
// d_out = out [16,2048,64] ++ w [16,2048,2048].
#define B_ 16
#define L_ 2048
#define D_ 64
#define NROWS (B_ * L_)

typedef _Float16 half8 __attribute__((ext_vector_type(8)));
typedef float    f32x4 __attribute__((ext_vector_type(4)));

__device__ __forceinline__ float fexp2(float x) {
    float r; asm("v_exp_f32 %0, %1" : "=v"(r) : "v"(x)); return r;
}
__device__ __forceinline__ unsigned umed3(unsigned a, unsigned b, unsigned c) {
    unsigned d; asm("v_med3_u32 %0, %1, %2, %3" : "=v"(d) : "v"(a), "v"(b), "v"(c));
    return d;
}
// monotone float -> uint order-preserving transform
__device__ __forceinline__ unsigned fkey(float x) {
    unsigned b = __float_as_uint(x);
    return b ^ ((unsigned)(((int)b) >> 31) | 0x80000000u);
}

// ---------------------------------------------------------------------------
// Kernel P: K fp32 -> fp16, row-major (row = 64 halves = 128 B).
// ---------------------------------------------------------------------------
__global__ __launch_bounds__(256)
void cvt_k(const float* __restrict__ k, _Float16* __restrict__ kext)
{
    size_t i = (size_t)blockIdx.x * 256 + threadIdx.x;   // 8 floats each
    const float4* src = reinterpret_cast<const float4*>(k) + i * 2;
    float4 a = src[0], b = src[1];
    half8 h = { (_Float16)a.x, (_Float16)a.y, (_Float16)a.z, (_Float16)a.w,
                (_Float16)b.x, (_Float16)b.y, (_Float16)b.z, (_Float16)b.w };
    *reinterpret_cast<half8*>(kext + i * 8) = h;
}

// ---------------------------------------------------------------------------
// Kernel A (single worker): per block of 32 q-rows:
//   phase 1: fp16 MFMA score sweep (keys from L2-resident kext, no LDS
//            staging) + online sum-exp2 + packed-uint top-4 ladder, with the
//            block's whole 256 KB w-slab zero-filled via one interleaved
//            nontemporal store per step;
//   phase 2: wk-pair merge via LDS + 16-lane tournament -> top-4 idx + Z
//            into LDS;
//   phase 3: exact fp32 rescore of the 4 candidates, weights, out row,
//            scatter nonzeros into the just-zeroed slab.
// Grid = 1024 blocks (= 4 blocks/CU, one dispatch wave).
// ---------------------------------------------------------------------------
__global__ __launch_bounds__(256)
void sdpa_all(const float* __restrict__ q,
              const float* __restrict__ k,
              const float* __restrict__ v,
              const _Float16* __restrict__ kext,
              float* __restrict__ out,
              float* __restrict__ wout)
{
    __shared__ float Ms[2][64][21];   // wk-merge scratch (pad 21: bank-spread)
    __shared__ int4  Ri[32];          // per-row top-4 indices
    __shared__ float Rz[32];          // per-row Z (sum exp2)

    const int bid  = blockIdx.x;
    const int tid  = threadIdx.x;
    const int b    = bid >> 6;           // batch
    const int row0 = (bid & 63) * 32;    // 32 rows per block
    const int w    = tid >> 6;
    const int lane = tid & 63;
    const int wr   = w & 1;              // row half (16 rows)
    const int wk   = w >> 1;             // key half (1024 keys)
    const int c    = lane & 15;
    const int g    = lane >> 4;

    // Q fragment (A operand): row (row0+16wr+c), k-slots d in [8g,8g+8)/[32+8g,..)
    const float CQ = 0.18033688011112042f;   // log2(e)/8
    half8 qf0, qf1;
    {
        const float* qr = q + ((size_t)(b * L_ + row0 + 16 * wr + c)) * D_ + 8 * g;
        float4 f0 = *reinterpret_cast<const float4*>(qr);
        float4 f1 = *reinterpret_cast<const float4*>(qr + 4);
        float4 f2 = *reinterpret_cast<const float4*>(qr + 32);
        float4 f3 = *reinterpret_cast<const float4*>(qr + 36);
        qf0 = half8{ (_Float16)(f0.x*CQ), (_Float16)(f0.y*CQ), (_Float16)(f0.z*CQ),
                     (_Float16)(f0.w*CQ), (_Float16)(f1.x*CQ), (_Float16)(f1.y*CQ),
                     (_Float16)(f1.z*CQ), (_Float16)(f1.w*CQ) };
        qf1 = half8{ (_Float16)(f2.x*CQ), (_Float16)(f2.y*CQ), (_Float16)(f2.z*CQ),
                     (_Float16)(f2.w*CQ), (_Float16)(f3.x*CQ), (_Float16)(f3.y*CQ),
                     (_Float16)(f3.z*CQ), (_Float16)(f3.w*CQ) };
    }

    const char* ke = (const char*)(kext + (size_t)b * L_ * D_);
    float* wb = wout + ((size_t)b * L_ + row0) * L_;    // this block's 256 KB slab

    float    Z[4]  = {0.f, 0.f, 0.f, 0.f};
    unsigned tl[4][4];
    #pragma unroll
    for (int r = 0; r < 4; ++r)
        #pragma unroll
        for (int s = 0; s < 4; ++s) tl[r][s] = 0u;

    const f32x4 zz = {0.f, 0.f, 0.f, 0.f};
    f32x4* wb4 = reinterpret_cast<f32x4*>(wb);

    // sweep 1024 keys (this wave's half), 16 keys per step
    #pragma unroll 4
    for (int t = 0; t < 64; ++t) {
        const int kl = wk * 1024 + t * 16 + c;            // key id in batch
        const char* kp = ke + (size_t)kl * 128 + g * 16;
        half8 b0 = *reinterpret_cast<const half8*>(kp);        // d [8g,8g+8)
        half8 b1 = *reinterpret_cast<const half8*>(kp + 64);   // d [32+8g,..)

        // interleaved slab zero-fill: 4 KB per block per step
        __builtin_nontemporal_store(zz, wb4 + t * 256 + tid);

        f32x4 a = {0.f, 0.f, 0.f, 0.f};
        a = __builtin_amdgcn_mfma_f32_16x16x32_f16(qf0, b0, a, 0, 0, 0);
        a = __builtin_amdgcn_mfma_f32_16x16x32_f16(qf1, b1, a, 0, 0, 0);

        #pragma unroll
        for (int r = 0; r < 4; ++r) {
            float sp = a[r];                  // log2-domain score
            Z[r] += fexp2(sp);
            unsigned pk = (fkey(sp) & 0xFFFFF800u) | (unsigned)kl;
            unsigned n1 = umed3(pk, tl[r][0], tl[r][1]);
            unsigned n2 = umed3(pk, tl[r][1], tl[r][2]);
            unsigned n3 = umed3(pk, tl[r][2], tl[r][3]);
            tl[r][0] = max(tl[r][0], pk);
            tl[r][1] = n1; tl[r][2] = n2; tl[r][3] = n3;
        }
    }

    // ---- wk-pair merge through LDS ----
    if (wk == 1) {
        #pragma unroll
        for (int r = 0; r < 4; ++r) {
            Ms[wr][lane][r] = Z[r];
            #pragma unroll
            for (int s = 0; s < 4; ++s)
                Ms[wr][lane][4 + r * 4 + s] = __uint_as_float(tl[r][s]);
        }
    }
    __syncthreads();   // also drains all fill stores (vmcnt(0) before barrier)

    if (wk == 0) {
        #pragma unroll
        for (int r = 0; r < 4; ++r) {
            float Zr = Z[r] + Ms[wr][lane][r];
            #pragma unroll
            for (int s = 0; s < 4; ++s) {
                unsigned pk = __float_as_uint(Ms[wr][lane][4 + r * 4 + s]);
                unsigned n1 = umed3(pk, tl[r][0], tl[r][1]);
                unsigned n2 = umed3(pk, tl[r][1], tl[r][2]);
                unsigned n3 = umed3(pk, tl[r][2], tl[r][3]);
                tl[r][0] = max(tl[r][0], pk);
                tl[r][1] = n1; tl[r][2] = n2; tl[r][3] = n3;
            }
            #pragma unroll
            for (int m = 8; m; m >>= 1) Zr += __shfl_xor(Zr, m, 16);

            // 16-lane tournament: global top-4 (packed keys unique)
            int p = 0;
            unsigned win[4];
            #pragma unroll
            for (int t4 = 0; t4 < 4; ++t4) {
                unsigned cand = (p == 0) ? tl[r][0] : (p == 1) ? tl[r][1]
                              : (p == 2) ? tl[r][2] : (p == 3) ? tl[r][3] : 0u;
                unsigned mv = cand;
                #pragma unroll
                for (int m = 8; m; m >>= 1) {
                    unsigned ov = __shfl_xor(mv, m, 16);
                    mv = mv > ov ? mv : ov;
                }
                win[t4] = mv;
                if (cand == mv) ++p;
            }

            if (c == 0) {
                int rr = 16 * wr + 4 * g + r;
                Ri[rr] = make_int4((int)(win[0] & 2047u), (int)(win[1] & 2047u),
                                   (int)(win[2] & 2047u), (int)(win[3] & 2047u));
                Rz[rr] = Zr;
            }
        }
    }
    __syncthreads();

    // ---- phase 3: exact fp32 rescore + weights + out + scatter ----
    // wave w handles rows 8w..8w+7; lane group g = candidate g, c = d/4 slot.
    const float* kb = k + (size_t)b * L_ * D_;
    const float* vb = v + (size_t)b * L_ * D_;
    #pragma unroll 2
    for (int rloc = 0; rloc < 8; ++rloc) {
        const int rr = w * 8 + rloc;
        const int gr = b * L_ + row0 + rr;
        int4  iv = Ri[rr];
        float Zr = Rz[rr];
        int myi = (g == 0) ? iv.x : (g == 1) ? iv.y : (g == 2) ? iv.z : iv.w;

        float4 qv = *reinterpret_cast<const float4*>(q + (size_t)gr * D_ + 4 * c);
        float4 kv = *reinterpret_cast<const float4*>(kb + (size_t)myi * D_ + 4 * c);
        float tp = qv.x * kv.x + qv.y * kv.y + qv.z * kv.z + qv.w * kv.w;
        #pragma unroll
        for (int m = 8; m; m >>= 1) tp += __shfl_xor(tp, m, 16);
        tp *= CQ;   // log2-domain exact score

        float t0 = __shfl(tp, 0), t1 = __shfl(tp, 16),
              t2 = __shfl(tp, 32), t3 = __shfl(tp, 48);

        // P_j = Z * p_j ; all w math scaled by Z (exactly equivalent)
        float P0 = fexp2(t0), P1 = fexp2(t1), P2 = fexp2(t2), P3 = fexp2(t3);
        float Pmin = fminf(fminf(P0, P1), fminf(P2, P3));
        float eZ = 1e-7f * Zr;
        float n0 = fmaxf(P0 - Pmin - eZ, 0.f);
        float n1 = fmaxf(P1 - Pmin - eZ, 0.f);
        float n2 = fmaxf(P2 - Pmin - eZ, 0.f);
        float n3 = fmaxf(P3 - Pmin - eZ, 0.f);
        float wi = 1.0f / (n0 + n1 + n2 + n3 + eZ);
        float w0 = n0 * wi, w1 = n1 * wi, w2 = n2 * wi, w3 = n3 * wi;

        float o = w0 * vb[(size_t)iv.x * D_ + lane]
                + w1 * vb[(size_t)iv.y * D_ + lane]
                + w2 * vb[(size_t)iv.z * D_ + lane]
                + w3 * vb[(size_t)iv.w * D_ + lane];
        out[(size_t)gr * D_ + lane] = o;

        if (lane < 4) {
            int   si = (lane == 0) ? iv.x : (lane == 1) ? iv.y
                     : (lane == 2) ? iv.z : iv.w;
            float sw = (lane == 0) ? w0 : (lane == 1) ? w1
                     : (lane == 2) ? w2 : w3;
            wout[(size_t)gr * L_ + si] = sw;   // w at the Pmin slot is exactly 0
        }
    }
}

extern "C" void kernel_launch(void* const* d_in, const int* in_sizes, int n_in,
                              void* d_out, int out_size, void* d_ws, size_t ws_size,
                              hipStream_t stream) {
    const float* q = (const float*)d_in[0];
    const float* k = (const float*)d_in[1];
    const float* v = (const float*)d_in[2];

    float* out  = (float*)d_out;
    float* wout = out + (size_t)B_ * L_ * D_;

    _Float16* kext = (_Float16*)d_ws;   // 4 MiB

    cvt_k<<<(B_ * L_ * D_) / (8 * 256), 256, 0, stream>>>(k, kext);

    sdpa_all<<<1024, 256, 0, stream>>>(q, k, v, kext, out, wout);
}